// Round 1
// baseline (257.673 us; speedup 1.0000x reference)
//
#include <hip/hip_runtime.h>
#include <math.h>

#define NCLS 21
#define NSORT 2048
#define NTHREADS 1024
#define SCORE_THRESH 0.05f
#define NMS_THRESH 0.3f

// Kernel A: per-ROI softmax + box decode, written directly into d_out in its
// final (20, R, 5) layout: [y1,x1,y2,x2,prob]. Non-kept rows are zeroed later
// by the NMS kernel (d_out is poisoned 0xAA before every launch, so every
// element is written by A, then selectively zeroed by B).
__global__ __launch_bounds__(256) void decode_kernel(
    const float* __restrict__ loc, const float* __restrict__ scores,
    const float* __restrict__ rois, const int* __restrict__ ph,
    const int* __restrict__ pw, float* __restrict__ out, int R)
{
    int r = blockIdx.x * blockDim.x + threadIdx.x;
    if (r >= R) return;
    float sh = (float)(*ph), sw = (float)(*pw);

    // softmax over 21 classes (max-subtracted, like jax.nn.softmax)
    float s[NCLS];
    float m = -INFINITY;
#pragma unroll
    for (int c = 0; c < NCLS; ++c) { s[c] = scores[r * NCLS + c]; m = fmaxf(m, s[c]); }
    float sum = 0.f;
#pragma unroll
    for (int c = 0; c < NCLS; ++c) { s[c] = expf(s[c] - m); sum += s[c]; }

    float y1 = rois[r * 4 + 0], x1 = rois[r * 4 + 1];
    float y2 = rois[r * 4 + 2], x2 = rois[r * 4 + 3];
    float h = y2 - y1, w = x2 - x1;
    float cy = y1 + 0.5f * h, cx = x1 + 0.5f * w;

    for (int c = 1; c < NCLS; ++c) {
        float dy = loc[r * (NCLS * 4) + c * 4 + 0] * 0.1f;
        float dx = loc[r * (NCLS * 4) + c * 4 + 1] * 0.1f;
        float dh = loc[r * (NCLS * 4) + c * 4 + 2] * 0.2f;
        float dw = loc[r * (NCLS * 4) + c * 4 + 3] * 0.2f;
        float ncy = dy * h + cy;
        float ncx = dx * w + cx;
        float nh = expf(dh) * h;
        float nw = expf(dw) * w;
        float by1 = ncy - 0.5f * nh;
        float bx1 = ncx - 0.5f * nw;
        float by2 = ncy + 0.5f * nh;
        float bx2 = ncx + 0.5f * nw;
        by1 = fminf(fmaxf(by1, 0.f), sh);
        by2 = fminf(fmaxf(by2, 0.f), sh);
        bx1 = fminf(fmaxf(bx1, 0.f), sw);
        bx2 = fminf(fmaxf(bx2, 0.f), sw);
        float* o = out + ((size_t)(c - 1) * R + r) * 5;
        o[0] = by1; o[1] = bx1; o[2] = by2; o[3] = bx2;
        o[4] = s[c] / sum;
    }
}

// Kernel B: one block per class. Bitonic-sort (score desc, idx asc) in LDS,
// greedy NMS with parallel suppression sweeps, then zero non-kept rows in
// place in d_out.
__global__ __launch_bounds__(NTHREADS) void nms_kernel(float* __restrict__ out, int R)
{
    __shared__ unsigned long long key[NSORT];     // 16 KB
    __shared__ float by1s[NSORT], bx1s[NSORT];    // 4 x 8 KB = 32 KB
    __shared__ float by2s[NSORT], bx2s[NSORT];
    __shared__ unsigned char removed[NSORT];      // 2 KB
    __shared__ unsigned char keepf[NSORT];        // 2 KB
    __shared__ int nvalid;

    int tid = threadIdx.x;
    int c = blockIdx.x;                 // class-1 index, 0..19
    float* slice = out + (size_t)c * R * 5;

    // Build sort keys. score in (0,1) so float bit order == value order for
    // nonneg floats; key = (~score_bits)<<32 | idx -> ascending u64 sort gives
    // descending score with ascending-idx tie-break (== stable jnp.argsort).
    for (int i = tid; i < NSORT; i += NTHREADS) {
        unsigned long long k;
        if (i < R) {
            float s = slice[i * 5 + 4];
            unsigned sb = __float_as_uint(s);
            k = ((unsigned long long)(~sb) << 32) | (unsigned)i;
        } else {
            k = ~0ull;                  // pads sort last
        }
        key[i] = k;
        removed[i] = 0;
        keepf[i] = 0;
    }
    if (tid == 0) nvalid = R;
    __syncthreads();

    // Bitonic sort, ascending u64.
    for (unsigned kk = 2; kk <= NSORT; kk <<= 1) {
        for (unsigned j = kk >> 1; j > 0; j >>= 1) {
            for (unsigned i = tid; i < NSORT; i += NTHREADS) {
                unsigned ixj = i ^ j;
                if (ixj > i) {
                    bool up = ((i & kk) == 0);
                    unsigned long long a = key[i], b = key[ixj];
                    if ((a > b) == up) { key[i] = b; key[ixj] = a; }
                }
            }
            __syncthreads();
        }
    }

    // Gather boxes into sorted order; find first invalid position.
    for (int i = tid; i < R; i += NTHREADS) {
        unsigned o = (unsigned)(key[i] & 0xffffffffu);
        by1s[i] = slice[o * 5 + 0];
        bx1s[i] = slice[o * 5 + 1];
        by2s[i] = slice[o * 5 + 2];
        bx2s[i] = slice[o * 5 + 3];
        float s = __uint_as_float(~(unsigned)(key[i] >> 32));
        if (!(s > SCORE_THRESH)) atomicMin(&nvalid, i);
    }
    __syncthreads();
    int nv = nvalid;

    // Greedy NMS: pivot over non-removed boxes in score order; each pivot
    // suppresses later boxes with IoU > 0.3 via a parallel sweep.
    for (int i = 0; i < nv; ++i) {
        if (removed[i]) continue;       // uniform read; no writes since last sync
        if (tid == 0) keepf[i] = 1;
        float iy1 = by1s[i], ix1 = bx1s[i], iy2 = by2s[i], ix2 = bx2s[i];
        float iarea = (iy2 - iy1) * (ix2 - ix1);
        for (int j = i + 1 + tid; j < nv; j += NTHREADS) {
            if (!removed[j]) {
                float jy1 = by1s[j], jx1 = bx1s[j];
                float jy2 = by2s[j], jx2 = bx2s[j];
                float ty1 = fmaxf(iy1, jy1);
                float tx1 = fmaxf(ix1, jx1);
                float ty2 = fminf(iy2, jy2);
                float tx2 = fminf(ix2, jx2);
                float ih = fmaxf(ty2 - ty1, 0.f);
                float iw = fmaxf(tx2 - tx1, 0.f);
                float inter = ih * iw;
                float jarea = (jy2 - jy1) * (jx2 - jx1);
                float uni = fmaxf(iarea + jarea - inter, 1e-10f);
                if (inter / uni > NMS_THRESH) removed[j] = 1;
            }
        }
        __syncthreads();
    }
    __syncthreads();

    // Zero the non-kept rows (covers removed, below-threshold, and all pads'
    // original slots since every original index appears exactly once in key).
    for (int i = tid; i < R; i += NTHREADS) {
        if (!keepf[i]) {
            unsigned o = (unsigned)(key[i] & 0xffffffffu);
            float* p = slice + (size_t)o * 5;
            p[0] = 0.f; p[1] = 0.f; p[2] = 0.f; p[3] = 0.f; p[4] = 0.f;
        }
    }
}

extern "C" void kernel_launch(void* const* d_in, const int* in_sizes, int n_in,
                              void* d_out, int out_size, void* d_ws, size_t ws_size,
                              hipStream_t stream) {
    const float* loc    = (const float*)d_in[0];   // (R, 84) f32
    const float* scores = (const float*)d_in[1];   // (R, 21) f32
    const float* rois   = (const float*)d_in[2];   // (R, 4)  f32
    const int*   ph     = (const int*)d_in[3];     // scalar int
    const int*   pw     = (const int*)d_in[4];     // scalar int
    float* out = (float*)d_out;                    // (20, R, 5) f32
    int R = in_sizes[2] / 4;

    decode_kernel<<<(R + 255) / 256, 256, 0, stream>>>(loc, scores, rois, ph, pw, out, R);
    nms_kernel<<<NCLS - 1, NTHREADS, 0, stream>>>(out, R);
}